// Round 19
// baseline (1737.435 us; speedup 1.0000x reference)
//
#include <hip/hip_runtime.h>
#include <math.h>

typedef unsigned short u16;
typedef unsigned int u32;
typedef __attribute__((ext_vector_type(8))) short bf16x8;
typedef __attribute__((ext_vector_type(16))) float f32x16;
typedef __attribute__((ext_vector_type(4))) float f4v;
typedef __attribute__((ext_vector_type(4))) u32 u32x4;

#define MFMA(a, b, c) __builtin_amdgcn_mfma_f32_32x32x16_bf16(a, b, c, 0, 0, 0)

#define SYNC_STEP() do {                                   \
    asm volatile("s_waitcnt vmcnt(0)" ::: "memory");       \
    __builtin_amdgcn_s_barrier();                          \
    __builtin_amdgcn_sched_barrier(0);                     \
} while (0)

// counted-vmcnt sync (T4)
#define SYNC_CNT_LIT(nlit) do {                                    \
    asm volatile("s_waitcnt vmcnt(" #nlit ")" ::: "memory");       \
    __builtin_amdgcn_s_barrier();                                  \
    __builtin_amdgcn_sched_barrier(0);                             \
} while (0)

// ---------------- helpers ----------------
__device__ __forceinline__ float bf2f(u16 h) { return __uint_as_float(((u32)h) << 16); }

__device__ __forceinline__ void split2(float v, u16& h, u16& l) {
    u32 u = __float_as_uint(v);
    u32 hr = (u + 0x7FFFu + ((u >> 16) & 1u)) & 0xFFFF0000u;
    h = (u16)(hr >> 16);
    float lf = v - __uint_as_float(hr);
    u32 ul = __float_as_uint(lf);
    l = (u16)((ul + 0x7FFFu + ((ul >> 16) & 1u)) >> 16);
}

__device__ __forceinline__ u32 cvtpk(float lo, float hi) {
    u32 r;
    asm("v_cvt_pk_bf16_f32 %0, %1, %2" : "=v"(r) : "v"(lo), "v"(hi));
    return r;
}

__device__ __forceinline__ void swap32(u32& a, u32& b, int hi) {
    u32 ta = (u32)__shfl_xor((int)a, 32);
    u32 tb = (u32)__shfl_xor((int)b, 32);
    u32 na = hi ? tb : a;
    u32 nb = hi ? b : ta;
    a = na; b = nb;
}

// P regs (f32, S^T layout) -> A-fragment hi + exact lo residual
__device__ __forceinline__ void repack(const f32x16& v, int base, int hi, bf16x8& fh, bf16x8& fl) {
    float p0 = v[base + 0], p1 = v[base + 1], p2 = v[base + 2], p3 = v[base + 3];
    float p4 = v[base + 4], p5 = v[base + 5], p6 = v[base + 6], p7 = v[base + 7];
    u32 X0 = cvtpk(p0, p1), X1 = cvtpk(p2, p3), X4 = cvtpk(p4, p5), X5 = cvtpk(p6, p7);
    float r0 = p0 - __uint_as_float(X0 << 16);
    float r1 = p1 - __uint_as_float(X0 & 0xFFFF0000u);
    float r2 = p2 - __uint_as_float(X1 << 16);
    float r3 = p3 - __uint_as_float(X1 & 0xFFFF0000u);
    float r4 = p4 - __uint_as_float(X4 << 16);
    float r5 = p5 - __uint_as_float(X4 & 0xFFFF0000u);
    float r6 = p6 - __uint_as_float(X5 << 16);
    float r7 = p7 - __uint_as_float(X5 & 0xFFFF0000u);
    u32 L0 = cvtpk(r0, r1), L1 = cvtpk(r2, r3), L4 = cvtpk(r4, r5), L5 = cvtpk(r6, r7);
    swap32(X0, X4, hi); swap32(X1, X5, hi);
    swap32(L0, L4, hi); swap32(L1, L5, hi);
    u32x4 th = {X0, X1, X4, X5};
    u32x4 tl = {L0, L1, L4, L5};
    fh = __builtin_bit_cast(bf16x8, th);
    fl = __builtin_bit_cast(bf16x8, tl);
}

// ---------------- PE table ----------------
__global__ __launch_bounds__(256) void pe_kernel(float* __restrict__ pe) {
    int idx = blockIdx.x * 256 + threadIdx.x;      // < 1024*768
    int n = idx / 768, d = idx - n * 768;
    float v = 0.0f;
    if (d < 384) {
        int pos = (d < 192) ? (n >> 5) : (n & 31);
        int dd  = (d < 192) ? d : d - 192;
        int j2  = dd & ~1;
        float dv  = expf((float)j2 * (-9.210340371976184f / 192.0f));
        float ang = (float)pos * dv;
        v = (dd & 1) ? cosf(ang) : sinf(ang);
    }
    pe[idx] = v;
}

// ---------------- patch gather ----------------
__global__ __launch_bounds__(256) void gather_kernel(const float* __restrict__ x,
                                                     u16* __restrict__ xph,
                                                     u16* __restrict__ xpl) {
    int idx = blockIdx.x * 256 + threadIdx.x;      // < 2048*768
    int m = idx / 768, col = idx - m * 768;
    int b = m >> 10, n = m & 1023;
    int ci = col >> 8, rem = col & 255;
    int pr = rem >> 4, pc = rem & 15;
    int hh = ((n >> 5) << 4) + pr;
    int ww = ((n & 31) << 4) + pc;
    float v = x[(((size_t)(b * 3 + ci) * 512) + hh) * 512 + ww];
    split2(v, xph[idx], xpl[idx]);
}

// ---------------- fp32 -> hi/lo split ----------------
__global__ __launch_bounds__(256) void fsplit(const float* __restrict__ in,
                                              u16* __restrict__ h, u16* __restrict__ l, int n4) {
    int i = blockIdx.x * 256 + threadIdx.x;
    if (i >= n4) return;
    float4 v = ((const float4*)in)[i];
    int o = i * 4;
    split2(v.x, h[o], l[o]);
    split2(v.y, h[o + 1], l[o + 1]);
    split2(v.z, h[o + 2], l[o + 2]);
    split2(v.w, h[o + 3], l[o + 3]);
}

// ---------------- per-layer weight split ----------------
__global__ __launch_bounds__(256) void wsplit_layer(const float* __restrict__ qkvw,
                                                    const float* __restrict__ projw,
                                                    const float* __restrict__ w1,
                                                    const float* __restrict__ w2,
                                                    u16* __restrict__ wh, u16* __restrict__ wl) {
    int i4 = blockIdx.x * 256 + threadIdx.x;       // < 1179648
    if (i4 >= 1179648) return;
    size_t idx = (size_t)i4 * 4;
    const float* src; size_t off;
    if (idx < 1769472)      { src = qkvw;  off = idx; }
    else if (idx < 2359296) { src = projw; off = idx - 1769472; }
    else if (idx < 3538944) { src = w1;    off = idx - 2359296; }
    else                    { src = w2;    off = idx - 3538944; }
    float4 v = *(const float4*)(src + off);
    split2(v.x, wh[idx], wl[idx]);
    split2(v.y, wh[idx + 1], wl[idx + 1]);
    split2(v.z, wh[idx + 2], wl[idx + 2]);
    split2(v.w, wh[idx + 3], wl[idx + 3]);
}

// ---------------- bias transpose ----------------
__global__ __launch_bounds__(256) void btrans(const float* __restrict__ src, float* __restrict__ dst) {
    __shared__ float tl[32][33];
    int bx = blockIdx.x & 31, by = blockIdx.x >> 5;
    int tx = threadIdx.x & 31, ty = threadIdx.x >> 5;
#pragma unroll
    for (int j = 0; j < 4; ++j)
        tl[ty + j * 8][tx] = src[(size_t)(by * 32 + ty + j * 8) * 1024 + bx * 32 + tx];
    __syncthreads();
#pragma unroll
    for (int j = 0; j < 4; ++j)
        dst[(size_t)(bx * 32 + ty + j * 8) * 1024 + by * 32 + tx] = tl[tx][ty + j * 8];
}

// ---------------- LayerNorm -> hi/lo ----------------
__global__ __launch_bounds__(256) void ln_kernel(const float* __restrict__ x,
                                                 const float* __restrict__ g,
                                                 const float* __restrict__ b,
                                                 u16* __restrict__ yh, u16* __restrict__ yl) {
    int row = blockIdx.x, tid = threadIdx.x;
    int wid = tid >> 6, lane = tid & 63;
    const float* xr = x + (size_t)row * 768;
    float v0 = xr[tid], v1 = xr[tid + 256], v2 = xr[tid + 512];
    __shared__ float ws[8];
    float sum = v0 + v1 + v2;
#pragma unroll
    for (int off = 32; off > 0; off >>= 1) sum += __shfl_xor(sum, off);
    if (lane == 0) ws[wid] = sum;
    __syncthreads();
    float mean = (ws[0] + ws[1] + ws[2] + ws[3]) * (1.0f / 768.0f);
    float d0 = v0 - mean, d1 = v1 - mean, d2 = v2 - mean;
    float vs = d0 * d0 + d1 * d1 + d2 * d2;
#pragma unroll
    for (int off = 32; off > 0; off >>= 1) vs += __shfl_xor(vs, off);
    if (lane == 0) ws[4 + wid] = vs;
    __syncthreads();
    float rstd = rsqrtf((ws[4] + ws[5] + ws[6] + ws[7]) * (1.0f / 768.0f) + 1e-5f);
    size_t o = (size_t)row * 768;
    split2(d0 * rstd * g[tid]       + b[tid],       yh[o + tid],       yl[o + tid]);
    split2(d1 * rstd * g[tid + 256] + b[tid + 256], yh[o + tid + 256], yl[o + tid + 256]);
    split2(d2 * rstd * g[tid + 512] + b[tid + 512], yh[o + tid + 512], yl[o + tid + 512]);
}

// full-slot-spread LDS chunk swizzle
__device__ __forceinline__ int mrow(int r) { return (r + (r >> 2)) & 3; }

// ---------------- gemm_sp: 64x128 tile, 4 waves of 32x64, 3-buf counted-vmcnt ----------------
template <int MODE>
__global__ __launch_bounds__(256, 2) void gemm_sp(const u16* __restrict__ Ah, const u16* __restrict__ Al,
                                                  const u16* __restrict__ Bh, const u16* __restrict__ Bl,
                                                  const float* __restrict__ bias,
                                                  const float* __restrict__ res,
                                                  const float* __restrict__ auxf,
                                                  const u16* __restrict__ auxh, const u16* __restrict__ auxl,
                                                  float* __restrict__ C, u16* __restrict__ Ch, u16* __restrict__ Cl,
                                                  int M, int N, int K, int nby) {
    __shared__ u16 SH[36864];
    u16* As = SH;
    u16* Bs = SH + 12288;
    int tid = threadIdx.x;
    int wid = tid >> 6, lane = tid & 63;
    int hi = lane >> 5;
    int lq = lane & 31;

    int nwg = gridDim.x;
    int q8 = nwg >> 3;
    int swz = (blockIdx.x & 7) * q8 + (blockIdx.x >> 3);
    int cb = swz / nby, rb = swz - cb * nby;
    int m0 = rb * 64, n0 = cb * 128;

    f32x16 acc0 = {}, acc1 = {};

    auto stage = [&](int buf, int kt) {
#pragma unroll
        for (int c = 0; c < 2; ++c) {
            const u16* G = c ? Al : Ah;
            int row = wid * 16 + (lane >> 2);
            int ch = (lane & 3) ^ mrow(row);
            const u16* g = G + (size_t)(m0 + row) * K + kt + ch * 8;
            __builtin_amdgcn_global_load_lds((const __attribute__((address_space(1))) u32*)g,
                                             (__attribute__((address_space(3))) u32*)&As[(buf * 2 + c) * 2048 + (wid * 16) * 32],
                                             16, 0, 0);
        }
#pragma unroll
        for (int c = 0; c < 2; ++c) {
            const u16* G = c ? Bl : Bh;
#pragma unroll
            for (int j = 0; j < 2; ++j) {
                int row = wid * 32 + j * 16 + (lane >> 2);
                int ch = (lane & 3) ^ mrow(row);
                const u16* g = G + (size_t)(n0 + row) * K + kt + ch * 8;
                __builtin_amdgcn_global_load_lds((const __attribute__((address_space(1))) u32*)g,
                                                 (__attribute__((address_space(3))) u32*)&Bs[(buf * 2 + c) * 4096 + (wid * 32 + j * 16) * 32],
                                                 16, 0, 0);
            }
        }
    };

    int ar  = (wid >> 1) * 32 + lq;
    int br0 = (wid & 1) * 64 + lq;
    int br1 = br0 + 32;

    auto compute = [&](int buf) {
#pragma unroll
        for (int kc = 0; kc < 2; ++kc) {
            int gc = (kc << 1) | hi;
            int oA  = ar  * 32 + ((gc ^ mrow(ar))  << 3);
            int oB0 = br0 * 32 + ((gc ^ mrow(br0)) << 3);
            int oB1 = br1 * 32 + ((gc ^ mrow(br1)) << 3);
            bf16x8 ah  = *(const bf16x8*)(As + (buf * 2 + 0) * 2048 + oA);
            bf16x8 al  = *(const bf16x8*)(As + (buf * 2 + 1) * 2048 + oA);
            bf16x8 b0h = *(const bf16x8*)(Bs + (buf * 2 + 0) * 4096 + oB0);
            bf16x8 b0l = *(const bf16x8*)(Bs + (buf * 2 + 1) * 4096 + oB0);
            bf16x8 b1h = *(const bf16x8*)(Bs + (buf * 2 + 0) * 4096 + oB1);
            bf16x8 b1l = *(const bf16x8*)(Bs + (buf * 2 + 1) * 4096 + oB1);
            acc0 = MFMA(ah, b0h, acc0);
            acc0 = MFMA(ah, b0l, acc0);
            acc0 = MFMA(al, b0h, acc0);
            acc1 = MFMA(ah, b1h, acc1);
            acc1 = MFMA(ah, b1l, acc1);
            acc1 = MFMA(al, b1h, acc1);
        }
    };

    int nk = K >> 5;
    stage(0, 0);
    stage(1, 32);
    int t = 0;
    for (; t < nk - 1; ++t) {
        SYNC_CNT_LIT(6);
        if (t + 2 < nk) stage((t + 2) % 3, (t + 2) << 5);
        compute(t % 3);
    }
    SYNC_STEP();
    compute(t % 3);

    auto epi = [&](const f32x16& a, int ncol) {
        int col = n0 + ncol + lq;
        int rb2 = m0 + (wid >> 1) * 32 + (hi << 2);
#pragma unroll
        for (int r = 0; r < 16; ++r) {
            int row = rb2 + (r & 3) + ((r >> 2) << 3);
            float v = a[r];
            size_t o = (size_t)row * N + col;
            if (MODE == 1) C[o] = v + bias[col] + auxf[(size_t)(row & 1023) * N + col];
            else if (MODE == 2) C[o] = res[o] + (bf2f(auxh[o]) + bf2f(auxl[o])) + v + bias[col];
            else if (MODE == 4) C[o] = res[o] + v + bias[col];
            else if (MODE == 5) {
                v += bias[col];
                v = fmaxf(v, 0.0f);
                split2(v, Ch[o], Cl[o]);
            }
            else if (MODE == 6) C[o] = v + bias[col];
        }
    };
    epi(acc0, (wid & 1) * 64);
    epi(acc1, (wid & 1) * 64 + 32);
}

// ---------------- gemm_sq: 128x128 tile, 4 waves of 64x64, 2-buf drain ----------------
template <int MODE>
__global__ __launch_bounds__(256, 2) void gemm_sq(const u16* __restrict__ Ah, const u16* __restrict__ Al,
                                                  const u16* __restrict__ Bh, const u16* __restrict__ Bl,
                                                  const float* __restrict__ bias,
                                                  u16* __restrict__ Ch, u16* __restrict__ Cl,
                                                  u16* __restrict__ Cth, u16* __restrict__ Ctl,
                                                  int M, int N, int K, int nby) {
    __shared__ u16 SH[32768];
    int tid = threadIdx.x;
    int wid = tid >> 6, lane = tid & 63;
    int hi = lane >> 5;
    int lq = lane & 31;
    int wm = wid >> 1, wn = wid & 1;

    int nwg = gridDim.x;
    int q8 = nwg >> 3;
    int swz = (blockIdx.x & 7) * q8 + (blockIdx.x >> 3);
    int cb = swz / nby, rb = swz - cb * nby;
    int m0 = rb * 128, n0 = cb * 128;

    f32x16 acc00 = {}, acc01 = {}, acc10 = {}, acc11 = {};

    const u16* srcs[4] = {Ah, Al, Bh, Bl};
    auto stage = [&](int buf, int kt) {
        const u16* G = srcs[wid];
        int rbase = (wid < 2) ? m0 : n0;
#pragma unroll
        for (int i = 0; i < 8; ++i) {
            int row = i * 16 + (lane >> 2);
            int ch = (lane & 3) ^ mrow(row);
            const u16* g = G + (size_t)(rbase + row) * K + kt + ch * 8;
            __builtin_amdgcn_global_load_lds((const __attribute__((address_space(1))) u32*)g,
                                             (__attribute__((address_space(3))) u32*)&SH[buf * 16384 + wid * 4096 + i * 512],
                                             16, 0, 0);
        }
    };

    int ar0 = wm * 64 + lq, ar1 = ar0 + 32;
    int br0 = wn * 64 + lq, br1 = br0 + 32;

    auto compute = [&](int buf) {
        const u16* SAh = SH + buf * 16384;
        const u16* SAl = SAh + 4096;
        const u16* SBh = SAl + 4096;
        const u16* SBl = SBh + 4096;
#pragma unroll
        for (int kc = 0; kc < 2; ++kc) {
            int gc = (kc << 1) | hi;
            int oA0 = ar0 * 32 + ((gc ^ mrow(ar0)) << 3);
            int oA1 = ar1 * 32 + ((gc ^ mrow(ar1)) << 3);
            int oB0 = br0 * 32 + ((gc ^ mrow(br0)) << 3);
            int oB1 = br1 * 32 + ((gc ^ mrow(br1)) << 3);
            bf16x8 a0h = *(const bf16x8*)(SAh + oA0);
            bf16x8 a0l = *(const bf16x8*)(SAl + oA0);
            bf16x8 a1h = *(const bf16x8*)(SAh + oA1);
            bf16x8 a1l = *(const bf16x8*)(SAl + oA1);
            bf16x8 b0h = *(const bf16x8*)(SBh + oB0);
            bf16x8 b0l = *(const bf16x8*)(SBl + oB0);
            bf16x8 b1h = *(const bf16x8*)(SBh + oB1);
            bf16x8 b1l = *(const bf16x8*)(SBl + oB1);
            acc00 = MFMA(a0h, b0h, acc00);
            acc00 = MFMA(a0h, b0l, acc00);
            acc00 = MFMA(a0l, b0h, acc00);
            acc01 = MFMA(a0h, b1h, acc01);
            acc01 = MFMA(a0h, b1l, acc01);
            acc01 = MFMA(a0l, b1h, acc01);
            acc10 = MFMA(a1h, b0h, acc10);
            acc10 = MFMA(a1h, b0l, acc10);
            acc10 = MFMA(a1l, b0h, acc10);
            acc11 = MFMA(a1h, b1h, acc11);
            acc11 = MFMA(a1h, b1l, acc11);
            acc11 = MFMA(a1l, b1h, acc11);
        }
    };

    int nk = K >> 5;
    stage(0, 0);
    for (int t = 0; t < nk; ++t) {
        SYNC_STEP();
        if (t + 1 < nk) stage((t + 1) & 1, (t + 1) << 5);
        compute(t & 1);
    }

    if (MODE == 7 && n0 >= 1536) {
        int bb = m0 >> 10;
        int nbase = m0 & 1023;
#pragma unroll
        for (int P = 0; P < 2; ++P) {
            __syncthreads();
            if (wm == P) {
                auto scat = [&](const f32x16& a, int fm, int fn) {
                    int c = wn * 64 + fn * 32 + lq;
                    int rbl = fm * 32 + (hi << 2);
#pragma unroll
                    for (int r = 0; r < 16; ++r) {
                        int rr = rbl + (r & 3) + ((r >> 2) << 3);
                        u16 hv, lv;
                        split2(a[r], hv, lv);
                        SH[c * 68 + rr] = hv;
                        SH[8704 + c * 68 + rr] = lv;
                    }
                };
                scat(acc00, 0, 0); scat(acc01, 0, 1); scat(acc10, 1, 0); scat(acc11, 1, 1);
            }
            __syncthreads();
#pragma unroll
            for (int pass = 0; pass < 4; ++pass) {
                int c2 = pass * 32 + (tid >> 3);
                int ch8 = tid & 7;
                int hcol = (n0 - 1536) + c2;
                int h2 = hcol >> 6, hd = hcol & 63;
                size_t dst = ((size_t)(bb * 12 + h2) * 64 + hd) * 1024 + nbase + P * 64 + ch8 * 8;
                int so = c2 * 68 + ch8 * 8;
                u32x4 ph = {*(const u32*)&SH[so], *(const u32*)&SH[so + 2],
                            *(const u32*)&SH[so + 4], *(const u32*)&SH[so + 6]};
                u32x4 pl = {*(const u32*)&SH[8704 + so], *(const u32*)&SH[8704 + so + 2],
                            *(const u32*)&SH[8704 + so + 4], *(const u32*)&SH[8704 + so + 6]};
                *(u32x4*)(Cth + dst) = ph;
                *(u32x4*)(Ctl + dst) = pl;
            }
        }
        return;
    }

    auto epi = [&](const f32x16& a, int fm, int fn) {
        int col = n0 + wn * 64 + fn * 32 + lq;
        int rb2 = m0 + wm * 64 + fm * 32 + (hi << 2);
#pragma unroll
        for (int r = 0; r < 16; ++r) {
            int row = rb2 + (r & 3) + ((r >> 2) << 3);
            float v = a[r];
            if (MODE == 3) {
                size_t o = (size_t)row * N + col;
                v += bias[col];
                v = 0.5f * v * (1.0f + erff(v * 0.70710678118654752f));
                split2(v, Ch[o], Cl[o]);
            } else if (MODE == 7) {
                size_t o7 = (size_t)row * 1536 + col;
                split2(v, Ch[o7], Cl[o7]);
            }
        }
    };
    epi(acc00, 0, 0); epi(acc01, 0, 1); epi(acc10, 1, 0); epi(acc11, 1, 1);
}

// ---------------- MFMA flash attention: 64-row K-tiles, 8 steps, reg-staged T14 pipeline ----------------
// grid 384 (8 xcd x 3 bh x 16 qt), 4 waves (s=role K/V, p=K-parity over 64-row tiles)
__global__ __launch_bounds__(256, 2) void attn_mfma(const u16* __restrict__ qh, const u16* __restrict__ ql,
                                                    const u16* __restrict__ vth, const u16* __restrict__ vtl,
                                                    const float* __restrict__ biasT,
                                                    u16* __restrict__ oh, u16* __restrict__ ol) {
    __shared__ u16 smem[2][4][4096];     // [p][Kh,Kl,Vh,Vl][64x64] = 64 KB
    int tid = threadIdx.x;
    int wid = tid >> 6, lane = tid & 63;
    int s = wid & 1, p = wid >> 1;
    int lq = lane & 31;
    int hi = lane >> 5;
    int id = blockIdx.x;
    int xcd = id & 7;
    int j = id >> 3;
    int bh = xcd * 3 + (j >> 4);
    int qt = j & 15;
    int b = bh / 12, h = bh % 12;
    int bq0 = qt * 64;
    int gq = bq0 + s * 32 + lq;
    size_t vbase = (size_t)bh * 65536;   // Vt [64 hd][1024 k]

    bf16x8 qfh[4], qfl[4];
    {
        size_t qo = (size_t)(b * 1024 + gq) * 1536 + h * 64 + hi * 8;
#pragma unroll
        for (int ks = 0; ks < 4; ++ks) {
            qfh[ks] = *(const bf16x8*)(qh + qo + ks * 16);
            qfl[ks] = *(const bf16x8*)(ql + qo + ks * 16);
        }
    }

    f32x16 oa = {}, ob = {};
    float m_i = -1e30f, l_i = 0.0f;

    // T14 async-STAGE: load next tile into regs (issued early), ds_write after barrier.
    // Wave role s: 0 -> K comps {0,1}; 1 -> V^T comps {2,3}. Same LDS layout/swizzle as DMA.
    bf16x8 sreg[16];
    auto stage_load = [&](int kb) {
        if (s == 0) {
#pragma unroll
            for (int c = 0; c < 2; ++c) {
                const u16* G = c ? ql : qh;
#pragma unroll
                for (int i = 0; i < 8; ++i) {
                    int r = 8 * i + (lane >> 3);
                    int cl = (lane & 7) ^ (r & 7);
                    sreg[c * 8 + i] = *(const bf16x8*)(G + (size_t)(b * 1024 + kb + r) * 1536 + 768 + h * 64 + cl * 8);
                }
            }
        } else {
#pragma unroll
            for (int c = 0; c < 2; ++c) {
                const u16* G = c ? vtl : vth;
#pragma unroll
                for (int i = 0; i < 8; ++i) {
                    int r = 8 * i + (lane >> 3);
                    int cl = (lane & 7) ^ (r & 7);
                    sreg[c * 8 + i] = *(const bf16x8*)(G + vbase + (size_t)r * 1024 + kb + cl * 8);
                }
            }
        }
    };
    auto stage_write = [&]() {
        int cb = s ? 2 : 0;
#pragma unroll
        for (int c = 0; c < 2; ++c)
#pragma unroll
            for (int i = 0; i < 8; ++i)
                *(bf16x8*)(&smem[p][cb + c][i * 512 + lane * 8]) = sreg[c * 8 + i];
    };

    auto compute = [&](int kb) {
        const u16* Kh = &smem[p][0][0];
        const u16* Kl = &smem[p][1][0];
        const u16* Vh = &smem[p][2][0];
        const u16* Vl = &smem[p][3][0];
        // bias loads (32, coalesced in q) — issued first, consumed after QK block
        const float* bbase = biasT + (size_t)(kb + 4 * hi) * 1024 + gq;
        float bb[32];
#pragma unroll
        for (int g2 = 0; g2 < 4; ++g2)
#pragma unroll
            for (int q = 0; q < 4; ++q) {
                bb[g2 * 4 + q]      = bbase[(size_t)(g2 * 8 + q) * 1024];
                bb[16 + g2 * 4 + q] = bbase[(size_t)(32 + g2 * 8 + q) * 1024];
            }
        // QK^T: sa = k-rows 0..31, sb = k-rows 32..63 (independent chains)
        f32x16 sa = {}, sb = {};
#pragma unroll
        for (int ks = 0; ks < 4; ++ks) {
            int offA = lq * 64 + (((2 * ks + hi) ^ (lq & 7)) << 3);
            int offB = offA + 2048;                 // row lq+32, same swizzle
            bf16x8 khA = *(const bf16x8*)(Kh + offA);
            bf16x8 klA = *(const bf16x8*)(Kl + offA);
            bf16x8 khB = *(const bf16x8*)(Kh + offB);
            bf16x8 klB = *(const bf16x8*)(Kl + offB);
            sa = MFMA(khA, qfh[ks], sa);
            sb = MFMA(khB, qfh[ks], sb);
            sa = MFMA(khA, qfl[ks], sa);
            sb = MFMA(khB, qfl[ks], sb);
            sa = MFMA(klA, qfh[ks], sa);
            sb = MFMA(klB, qfh[ks], sb);
        }
        // V fragments (ds_read latency hides under softmax)
        bf16x8 vf[4][4];
#pragma unroll
        for (int kslot = 0; kslot < 4; ++kslot) {
            int off0 = lq * 64 + (((2 * kslot + hi) ^ (lq & 7)) << 3);
            int off1 = off0 + 2048;
            vf[kslot][0] = *(const bf16x8*)(Vh + off0);
            vf[kslot][1] = *(const bf16x8*)(Vh + off1);
            vf[kslot][2] = *(const bf16x8*)(Vl + off0);
            vf[kslot][3] = *(const bf16x8*)(Vl + off1);
        }
        // scale + bias
#pragma unroll
        for (int r = 0; r < 16; ++r) {
            sa[r] = sa[r] * 0.125f + bb[r];
            sb[r] = sb[r] * 0.125f + bb[16 + r];
        }
        // softmax over 64 keys (lane <-> q)
        float pm = fmaxf(sa[0], sb[0]);
#pragma unroll
        for (int r = 1; r < 16; ++r) pm = fmaxf(pm, fmaxf(sa[r], sb[r]));
        pm = fmaxf(pm, __shfl_xor(pm, 32));
        if (__any(pm > m_i + 8.0f)) {
            float mnew = fmaxf(m_i, pm);
            float scl = __expf(m_i - mnew);
            m_i = mnew;
            l_i *= scl;
#pragma unroll
            for (int r = 0; r < 16; ++r) {
                int qr = (r & 3) + 8 * (r >> 2) + 4 * hi;
                float fr = __shfl(scl, qr);
                oa[r] *= fr; ob[r] *= fr;
            }
        }
        float ls = 0.0f;
#pragma unroll
        for (int r = 0; r < 16; ++r) {
            sa[r] = __expf(sa[r] - m_i); ls += sa[r];
            sb[r] = __expf(sb[r] - m_i); ls += sb[r];
        }
        ls += __shfl_xor(ls, 32);
        l_i += ls;
        // P repack + PV, 4 k-slots
#pragma unroll
        for (int kslot = 0; kslot < 4; ++kslot) {
            bf16x8 ph, pl;
            if (kslot < 2) repack(sa, (kslot & 1) * 8, hi, ph, pl);
            else           repack(sb, (kslot & 1) * 8, hi, ph, pl);
            oa = MFMA(ph, vf[kslot][0], oa);
            oa = MFMA(ph, vf[kslot][2], oa);
            oa = MFMA(pl, vf[kslot][0], oa);
            ob = MFMA(ph, vf[kslot][1], ob);
            ob = MFMA(ph, vf[kslot][3], ob);
            ob = MFMA(pl, vf[kslot][1], ob);
        }
    };

    // parity p handles 64-row tiles kt = 2*ss+p, ss = 0..7
    stage_load(p * 64);
    asm volatile("s_waitcnt vmcnt(0)" ::: "memory");
    stage_write();
    __syncthreads();
    for (int ss = 0; ss < 8; ++ss) {
        if (ss + 1 < 8) stage_load((2 * (ss + 1) + p) * 64);   // flies under compute
        compute((2 * ss + p) * 64);
        __syncthreads();                     // readers done -> safe to overwrite
        if (ss + 1 < 8) {
            asm volatile("s_waitcnt vmcnt(0)" ::: "memory");   // own loads landed long ago
            stage_write();
        }
        __syncthreads();                     // writes visible
    }

    // ---- merge K-parity halves (smem reused as scratch; compute all done) ----
    float* mlb = (float*)((char*)smem + 32768);   // [s][p][2][32] floats
    mlb[((s * 2 + p) * 2 + 0) * 32 + lq] = m_i;
    mlb[((s * 2 + p) * 2 + 1) * 32 + lq] = l_i;
    __syncthreads();
    float mo  = mlb[((s * 2 + (p ^ 1)) * 2 + 0) * 32 + lq];
    float lo_ = mlb[((s * 2 + (p ^ 1)) * 2 + 1) * 32 + lq];
    float M = fmaxf(m_i, mo);
    float ea = __expf(m_i - M), eb = __expf(mo - M);
    float L = ea * l_i + eb * lo_;
    float f = ea / L;
    float frv[16];
#pragma unroll
    for (int r = 0; r < 16; ++r) frv[r] = __shfl(f, (r & 3) + 8 * (r >> 2) + 4 * hi);
    float* ox = (float*)((char*)smem + s * 8192);  // 32q x 64hd f32 per s
    if (p == 1) {
#pragma unroll
        for (int r = 0; r < 16; ++r) {
            int qr = (r & 3) + 8 * (r >> 2) + 4 * hi;
            ox[qr * 64 + lq] = oa[r] * frv[r];
            ox[qr * 64 + 32 + lq] = ob[r] * frv[r];
        }
    }
    __syncthreads();
    if (p == 0) {
#pragma unroll
        for (int r = 0; r < 16; ++r) {
            int qr = (r & 3) + 8 * (r >> 2) + 4 * hi;
            float va = oa[r] * frv[r] + ox[qr * 64 + lq];
            float vb = ob[r] * frv[r] + ox[qr * 64 + 32 + lq];
            size_t d = (size_t)(b * 1024 + bq0 + s * 32 + qr) * 768 + h * 64;
            split2(va, oh[d + lq], ol[d + lq]);
            split2(vb, oh[d + 32 + lq], ol[d + 32 + lq]);
        }
    }
}

// ---------------- fold + attention gate ----------------
__global__ __launch_bounds__(256) void fold_gate(const float* __restrict__ hbuf,
                                                 const float* __restrict__ xin,
                                                 const float* __restrict__ wg,
                                                 const float* __restrict__ bngw,
                                                 const float* __restrict__ bngb,
                                                 const float* __restrict__ wx,
                                                 const float* __restrict__ bnxw,
                                                 const float* __restrict__ bnxb,
                                                 const float* __restrict__ psiw,
                                                 const float* __restrict__ psib,
                                                 float* __restrict__ out) {
    int idx = blockIdx.x * 256 + threadIdx.x;      // < 2*512*512
    int b = idx >> 18;
    int rem = idx & 262143;
    int hh = rem >> 9, ww = rem & 511;
    int n = ((hh >> 4) << 5) + (ww >> 4);
    int pr = hh & 15, pc = ww & 15;
    const float* hrow = hbuf + (size_t)(b * 1024 + n) * 768 + pr * 16 + pc;
    float g0 = hrow[0], g1 = hrow[256], g2 = hrow[512];
    size_t xoff = ((size_t)(b * 3) * 512 + hh) * 512 + ww;
    float x0 = xin[xoff], x1 = xin[xoff + 262144], x2 = xin[xoff + 524288];
    float inv = rsqrtf(1.0f + 1e-5f);
    float gg = (g0 * wg[0] + g1 * wg[1] + g2 * wg[2]) * inv * bngw[0] + bngb[0];
    float xx = (x0 * wx[0] + x1 * wx[1] + x2 * wx[2]) * inv * bnxw[0] + bnxb[0];
    float z = gg + xx;
    z = z > 0.0f ? z : 0.0f;
    float psi = 1.0f / (1.0f + expf(-(z * psiw[0] + psib[0])));
    out[xoff]          = g0 * x0 * psi;
    out[xoff + 262144] = g1 * x1 * psi;
    out[xoff + 524288] = g2 * x2 * psi;
}

// ---------------- launch ----------------
extern "C" void kernel_launch(void* const* d_in, const int* in_sizes, int n_in,
                              void* d_out, int out_size, void* d_ws, size_t ws_size,
                              hipStream_t stream) {
    (void)in_sizes; (void)n_in; (void)out_size; (void)ws_size;
    const float* x       = (const float*)d_in[0];
    const float* conv_w  = (const float*)d_in[1];
    const float* conv_b  = (const float*)d_in[2];
    const float* ln1_g   = (const float*)d_in[3];
    const float* ln1_b   = (const float*)d_in[4];
    const float* qkv_w   = (const float*)d_in[5];
    const float* proj_w  = (const float*)d_in[6];
    const float* proj_b  = (const float*)d_in[7];
    const float* attn_bs = (const float*)d_in[8];
    const float* ln2_g   = (const float*)d_in[9];
    const float* ln2_b   = (const float*)d_in[10];
    const float* mlp_w1  = (const float*)d_in[11];
    const float* mlp_b1  = (const float*)d_in[12];
    const float* mlp_w2  = (const float*)d_in[13];
    const float* mlp_b2  = (const float*)d_in[14];
    const float* op_w1   = (const float*)d_in[15];
    const float* op_b1   = (const float*)d_in[16];
    const float* op_w2   = (const float*)d_in[17];
    const float* op_b2   = (const float*)d_in[18];
    const float* ag_wg   = (const float*)d_in[19];
    const float* ag_bngw = (const float*)d_in[20];
    const float* ag_bngb = (const float*)d_in[21];
    const float* ag_wx   = (const float*)d_in[22];
    const float* ag_bnxw = (const float*)d_in[23];
    const float* ag_bnxb = (const float*)d_in[24];
    const float* ag_psiw = (const float*)d_in[25];
    const float* ag_psib = (const float*)d_in[26];
    float* out = (float*)d_out;

    // workspace layout (bytes), total 67,108,864
    char* w8 = (char*)d_ws;
    float* t     = (float*)(w8);                      // 6,291,456
    u16* yh      = (u16*)(w8 + 6291456);
    u16* yl      = (u16*)(w8 + 9437184);
    u16* ath     = (u16*)(w8 + 12582912);
    u16* atl     = (u16*)(w8 + 15728640);
    u16* mh      = (u16*)(w8 + 18874368);             // 6,291,456
    u16* ml      = (u16*)(w8 + 25165824);             // 6,291,456
    u16* qh      = (u16*)(w8 + 31457280);             // 6,291,456 (2048x1536 u16)
    u16* ql      = (u16*)(w8 + 37748736);             // 6,291,456
    u16* wh      = (u16*)(w8 + 44040192);             // 9,437,184
    u16* wl      = (u16*)(w8 + 53477376);             // 9,437,184
    float* biasT = (float*)(w8 + 62914560);           // 4,194,304
    float* pe  = (float*)qh;
    u16* xph = mh; u16* xpl = ml;
    u16* vth = mh; u16* vtl = ml;
    float* oph2 = (float*)qh;
    u16* o1h = ath; u16* o1l = atl;

    const size_t W_QKV = 0, W_PROJ = 1769472, W_MLP1 = 2359296, W_MLP2 = 3538944;

    pe_kernel<<<3072, 256, 0, stream>>>(pe);
    gather_kernel<<<6144, 256, 0, stream>>>(x, xph, xpl);
    fsplit<<<576, 256, 0, stream>>>(conv_w, wh, wl, 147456);
    gemm_sp<1><<<192, 256, 0, stream>>>(xph, xpl, wh, wl, conv_b, nullptr, pe,
                                        nullptr, nullptr, t, nullptr, nullptr, 2048, 768, 768, 32);

    for (int l = 0; l < 8; ++l) {
        wsplit_layer<<<4608, 256, 0, stream>>>(qkv_w + (size_t)l * 1769472, proj_w + (size_t)l * 589824,
                                               mlp_w1 + (size_t)l * 1179648, mlp_w2 + (size_t)l * 1179648,
                                               wh, wl);
        btrans<<<1024, 256, 0, stream>>>(attn_bs + (size_t)l * 1048576, biasT);
        ln_kernel<<<2048, 256, 0, stream>>>(t, ln1_g + l * 768, ln1_b + l * 768, yh, yl);
        gemm_sq<7><<<288, 256, 0, stream>>>(yh, yl, wh + W_QKV, wl + W_QKV, nullptr,
                                            qh, ql, vth, vtl, 2048, 2304, 768, 16);
        attn_mfma<<<384, 256, 0, stream>>>(qh, ql, vth, vtl, biasT, ath, atl);
        gemm_sp<2><<<192, 256, 0, stream>>>(ath, atl, wh + W_PROJ, wl + W_PROJ, proj_b + l * 768,
                                            t, nullptr, yh, yl, t, nullptr, nullptr, 2048, 768, 768, 32);
        ln_kernel<<<2048, 256, 0, stream>>>(t, ln2_g + l * 768, ln2_b + l * 768, yh, yl);
        gemm_sq<3><<<192, 256, 0, stream>>>(yh, yl, wh + W_MLP1, wl + W_MLP1, mlp_b1 + l * 1536,
                                            mh, ml, nullptr, nullptr, 2048, 1536, 768, 16);
        gemm_sp<4><<<192, 256, 0, stream>>>(mh, ml, wh + W_MLP2, wl + W_MLP2, mlp_b2 + l * 768,
                                            t, nullptr, nullptr, nullptr, t, nullptr, nullptr,
                                            2048, 768, 1536, 32);
    }

    // output head
    fsplit<<<1536, 256, 0, stream>>>(t, yh, yl, 393216);
    fsplit<<<96, 256, 0, stream>>>(op_w1, wh, wl, 24576);
    fsplit<<<96, 256, 0, stream>>>(op_w2, wh + 131072, wl + 131072, 24576);
    gemm_sp<5><<<32, 256, 0, stream>>>(yh, yl, wh, wl, op_b1, nullptr, nullptr,
                                       nullptr, nullptr, nullptr, o1h, o1l, 2048, 128, 768, 32);
    gemm_sp<6><<<192, 256, 0, stream>>>(o1h, o1l, wh + 131072, wl + 131072, op_b2, nullptr,
                                        nullptr, nullptr, nullptr, oph2, nullptr, nullptr,
                                        2048, 768, 128, 32);
    fold_gate<<<2048, 256, 0, stream>>>(oph2, x, ag_wg, ag_bngw, ag_bngb,
                                        ag_wx, ag_bnxw, ag_bnxb, ag_psiw, ag_psib, out);
}

// Round 20
// 1390.962 us; speedup vs baseline: 1.2491x; 1.2491x over previous
//
#include <hip/hip_runtime.h>
#include <math.h>

typedef unsigned short u16;
typedef unsigned int u32;
typedef __attribute__((ext_vector_type(8))) short bf16x8;
typedef __attribute__((ext_vector_type(16))) float f32x16;
typedef __attribute__((ext_vector_type(4))) float f4v;
typedef __attribute__((ext_vector_type(4))) u32 u32x4;

#define MFMA(a, b, c) __builtin_amdgcn_mfma_f32_32x32x16_bf16(a, b, c, 0, 0, 0)

#define SYNC_STEP() do {                                   \
    asm volatile("s_waitcnt vmcnt(0)" ::: "memory");       \
    __builtin_amdgcn_s_barrier();                          \
    __builtin_amdgcn_sched_barrier(0);                     \
} while (0)

// counted-vmcnt sync (T4)
#define SYNC_CNT_LIT(nlit) do {                                    \
    asm volatile("s_waitcnt vmcnt(" #nlit ")" ::: "memory");       \
    __builtin_amdgcn_s_barrier();                                  \
    __builtin_amdgcn_sched_barrier(0);                             \
} while (0)

// ---------------- helpers ----------------
__device__ __forceinline__ float bf2f(u16 h) { return __uint_as_float(((u32)h) << 16); }

__device__ __forceinline__ void split2(float v, u16& h, u16& l) {
    u32 u = __float_as_uint(v);
    u32 hr = (u + 0x7FFFu + ((u >> 16) & 1u)) & 0xFFFF0000u;
    h = (u16)(hr >> 16);
    float lf = v - __uint_as_float(hr);
    u32 ul = __float_as_uint(lf);
    l = (u16)((ul + 0x7FFFu + ((ul >> 16) & 1u)) >> 16);
}

__device__ __forceinline__ u32 cvtpk(float lo, float hi) {
    u32 r;
    asm("v_cvt_pk_bf16_f32 %0, %1, %2" : "=v"(r) : "v"(lo), "v"(hi));
    return r;
}

__device__ __forceinline__ void swap32(u32& a, u32& b, int hi) {
    u32 ta = (u32)__shfl_xor((int)a, 32);
    u32 tb = (u32)__shfl_xor((int)b, 32);
    u32 na = hi ? tb : a;
    u32 nb = hi ? b : ta;
    a = na; b = nb;
}

// P regs (f32, S^T layout) -> A-fragment hi + exact lo residual
__device__ __forceinline__ void repack(const f32x16& v, int base, int hi, bf16x8& fh, bf16x8& fl) {
    float p0 = v[base + 0], p1 = v[base + 1], p2 = v[base + 2], p3 = v[base + 3];
    float p4 = v[base + 4], p5 = v[base + 5], p6 = v[base + 6], p7 = v[base + 7];
    u32 X0 = cvtpk(p0, p1), X1 = cvtpk(p2, p3), X4 = cvtpk(p4, p5), X5 = cvtpk(p6, p7);
    float r0 = p0 - __uint_as_float(X0 << 16);
    float r1 = p1 - __uint_as_float(X0 & 0xFFFF0000u);
    float r2 = p2 - __uint_as_float(X1 << 16);
    float r3 = p3 - __uint_as_float(X1 & 0xFFFF0000u);
    float r4 = p4 - __uint_as_float(X4 << 16);
    float r5 = p5 - __uint_as_float(X4 & 0xFFFF0000u);
    float r6 = p6 - __uint_as_float(X5 << 16);
    float r7 = p7 - __uint_as_float(X5 & 0xFFFF0000u);
    u32 L0 = cvtpk(r0, r1), L1 = cvtpk(r2, r3), L4 = cvtpk(r4, r5), L5 = cvtpk(r6, r7);
    swap32(X0, X4, hi); swap32(X1, X5, hi);
    swap32(L0, L4, hi); swap32(L1, L5, hi);
    u32x4 th = {X0, X1, X4, X5};
    u32x4 tl = {L0, L1, L4, L5};
    fh = __builtin_bit_cast(bf16x8, th);
    fl = __builtin_bit_cast(bf16x8, tl);
}

// ---------------- PE table ----------------
__global__ __launch_bounds__(256) void pe_kernel(float* __restrict__ pe) {
    int idx = blockIdx.x * 256 + threadIdx.x;      // < 1024*768
    int n = idx / 768, d = idx - n * 768;
    float v = 0.0f;
    if (d < 384) {
        int pos = (d < 192) ? (n >> 5) : (n & 31);
        int dd  = (d < 192) ? d : d - 192;
        int j2  = dd & ~1;
        float dv  = expf((float)j2 * (-9.210340371976184f / 192.0f));
        float ang = (float)pos * dv;
        v = (dd & 1) ? cosf(ang) : sinf(ang);
    }
    pe[idx] = v;
}

// ---------------- patch gather ----------------
__global__ __launch_bounds__(256) void gather_kernel(const float* __restrict__ x,
                                                     u16* __restrict__ xph,
                                                     u16* __restrict__ xpl) {
    int idx = blockIdx.x * 256 + threadIdx.x;      // < 2048*768
    int m = idx / 768, col = idx - m * 768;
    int b = m >> 10, n = m & 1023;
    int ci = col >> 8, rem = col & 255;
    int pr = rem >> 4, pc = rem & 15;
    int hh = ((n >> 5) << 4) + pr;
    int ww = ((n & 31) << 4) + pc;
    float v = x[(((size_t)(b * 3 + ci) * 512) + hh) * 512 + ww];
    split2(v, xph[idx], xpl[idx]);
}

// ---------------- fp32 -> hi/lo split ----------------
__global__ __launch_bounds__(256) void fsplit(const float* __restrict__ in,
                                              u16* __restrict__ h, u16* __restrict__ l, int n4) {
    int i = blockIdx.x * 256 + threadIdx.x;
    if (i >= n4) return;
    float4 v = ((const float4*)in)[i];
    int o = i * 4;
    split2(v.x, h[o], l[o]);
    split2(v.y, h[o + 1], l[o + 1]);
    split2(v.z, h[o + 2], l[o + 2]);
    split2(v.w, h[o + 3], l[o + 3]);
}

// ---------------- per-layer weight split ----------------
__global__ __launch_bounds__(256) void wsplit_layer(const float* __restrict__ qkvw,
                                                    const float* __restrict__ projw,
                                                    const float* __restrict__ w1,
                                                    const float* __restrict__ w2,
                                                    u16* __restrict__ wh, u16* __restrict__ wl) {
    int i4 = blockIdx.x * 256 + threadIdx.x;       // < 1179648
    if (i4 >= 1179648) return;
    size_t idx = (size_t)i4 * 4;
    const float* src; size_t off;
    if (idx < 1769472)      { src = qkvw;  off = idx; }
    else if (idx < 2359296) { src = projw; off = idx - 1769472; }
    else if (idx < 3538944) { src = w1;    off = idx - 2359296; }
    else                    { src = w2;    off = idx - 3538944; }
    float4 v = *(const float4*)(src + off);
    split2(v.x, wh[idx], wl[idx]);
    split2(v.y, wh[idx + 1], wl[idx + 1]);
    split2(v.z, wh[idx + 2], wl[idx + 2]);
    split2(v.w, wh[idx + 3], wl[idx + 3]);
}

// ---------------- bias transpose ----------------
__global__ __launch_bounds__(256) void btrans(const float* __restrict__ src, float* __restrict__ dst) {
    __shared__ float tl[32][33];
    int bx = blockIdx.x & 31, by = blockIdx.x >> 5;
    int tx = threadIdx.x & 31, ty = threadIdx.x >> 5;
#pragma unroll
    for (int j = 0; j < 4; ++j)
        tl[ty + j * 8][tx] = src[(size_t)(by * 32 + ty + j * 8) * 1024 + bx * 32 + tx];
    __syncthreads();
#pragma unroll
    for (int j = 0; j < 4; ++j)
        dst[(size_t)(bx * 32 + ty + j * 8) * 1024 + by * 32 + tx] = tl[tx][ty + j * 8];
}

// ---------------- LayerNorm -> hi/lo ----------------
__global__ __launch_bounds__(256) void ln_kernel(const float* __restrict__ x,
                                                 const float* __restrict__ g,
                                                 const float* __restrict__ b,
                                                 u16* __restrict__ yh, u16* __restrict__ yl) {
    int row = blockIdx.x, tid = threadIdx.x;
    int wid = tid >> 6, lane = tid & 63;
    const float* xr = x + (size_t)row * 768;
    float v0 = xr[tid], v1 = xr[tid + 256], v2 = xr[tid + 512];
    __shared__ float ws[8];
    float sum = v0 + v1 + v2;
#pragma unroll
    for (int off = 32; off > 0; off >>= 1) sum += __shfl_xor(sum, off);
    if (lane == 0) ws[wid] = sum;
    __syncthreads();
    float mean = (ws[0] + ws[1] + ws[2] + ws[3]) * (1.0f / 768.0f);
    float d0 = v0 - mean, d1 = v1 - mean, d2 = v2 - mean;
    float vs = d0 * d0 + d1 * d1 + d2 * d2;
#pragma unroll
    for (int off = 32; off > 0; off >>= 1) vs += __shfl_xor(vs, off);
    if (lane == 0) ws[4 + wid] = vs;
    __syncthreads();
    float rstd = rsqrtf((ws[4] + ws[5] + ws[6] + ws[7]) * (1.0f / 768.0f) + 1e-5f);
    size_t o = (size_t)row * 768;
    split2(d0 * rstd * g[tid]       + b[tid],       yh[o + tid],       yl[o + tid]);
    split2(d1 * rstd * g[tid + 256] + b[tid + 256], yh[o + tid + 256], yl[o + tid + 256]);
    split2(d2 * rstd * g[tid + 512] + b[tid + 512], yh[o + tid + 512], yl[o + tid + 512]);
}

// full-slot-spread LDS chunk swizzle
__device__ __forceinline__ int mrow(int r) { return (r + (r >> 2)) & 3; }

// ---------------- gemm_sp: 64x128 tile, 4 waves of 32x64, 3-buf counted-vmcnt ----------------
template <int MODE>
__global__ __launch_bounds__(256, 2) void gemm_sp(const u16* __restrict__ Ah, const u16* __restrict__ Al,
                                                  const u16* __restrict__ Bh, const u16* __restrict__ Bl,
                                                  const float* __restrict__ bias,
                                                  const float* __restrict__ res,
                                                  const float* __restrict__ auxf,
                                                  const u16* __restrict__ auxh, const u16* __restrict__ auxl,
                                                  float* __restrict__ C, u16* __restrict__ Ch, u16* __restrict__ Cl,
                                                  int M, int N, int K, int nby) {
    __shared__ u16 SH[36864];
    u16* As = SH;
    u16* Bs = SH + 12288;
    int tid = threadIdx.x;
    int wid = tid >> 6, lane = tid & 63;
    int hi = lane >> 5;
    int lq = lane & 31;

    int nwg = gridDim.x;
    int q8 = nwg >> 3;
    int swz = (blockIdx.x & 7) * q8 + (blockIdx.x >> 3);
    int cb = swz / nby, rb = swz - cb * nby;
    int m0 = rb * 64, n0 = cb * 128;

    f32x16 acc0 = {}, acc1 = {};

    auto stage = [&](int buf, int kt) {
#pragma unroll
        for (int c = 0; c < 2; ++c) {
            const u16* G = c ? Al : Ah;
            int row = wid * 16 + (lane >> 2);
            int ch = (lane & 3) ^ mrow(row);
            const u16* g = G + (size_t)(m0 + row) * K + kt + ch * 8;
            __builtin_amdgcn_global_load_lds((const __attribute__((address_space(1))) u32*)g,
                                             (__attribute__((address_space(3))) u32*)&As[(buf * 2 + c) * 2048 + (wid * 16) * 32],
                                             16, 0, 0);
        }
#pragma unroll
        for (int c = 0; c < 2; ++c) {
            const u16* G = c ? Bl : Bh;
#pragma unroll
            for (int j = 0; j < 2; ++j) {
                int row = wid * 32 + j * 16 + (lane >> 2);
                int ch = (lane & 3) ^ mrow(row);
                const u16* g = G + (size_t)(n0 + row) * K + kt + ch * 8;
                __builtin_amdgcn_global_load_lds((const __attribute__((address_space(1))) u32*)g,
                                                 (__attribute__((address_space(3))) u32*)&Bs[(buf * 2 + c) * 4096 + (wid * 32 + j * 16) * 32],
                                                 16, 0, 0);
            }
        }
    };

    int ar  = (wid >> 1) * 32 + lq;
    int br0 = (wid & 1) * 64 + lq;
    int br1 = br0 + 32;

    auto compute = [&](int buf) {
#pragma unroll
        for (int kc = 0; kc < 2; ++kc) {
            int gc = (kc << 1) | hi;
            int oA  = ar  * 32 + ((gc ^ mrow(ar))  << 3);
            int oB0 = br0 * 32 + ((gc ^ mrow(br0)) << 3);
            int oB1 = br1 * 32 + ((gc ^ mrow(br1)) << 3);
            bf16x8 ah  = *(const bf16x8*)(As + (buf * 2 + 0) * 2048 + oA);
            bf16x8 al  = *(const bf16x8*)(As + (buf * 2 + 1) * 2048 + oA);
            bf16x8 b0h = *(const bf16x8*)(Bs + (buf * 2 + 0) * 4096 + oB0);
            bf16x8 b0l = *(const bf16x8*)(Bs + (buf * 2 + 1) * 4096 + oB0);
            bf16x8 b1h = *(const bf16x8*)(Bs + (buf * 2 + 0) * 4096 + oB1);
            bf16x8 b1l = *(const bf16x8*)(Bs + (buf * 2 + 1) * 4096 + oB1);
            acc0 = MFMA(ah, b0h, acc0);
            acc0 = MFMA(ah, b0l, acc0);
            acc0 = MFMA(al, b0h, acc0);
            acc1 = MFMA(ah, b1h, acc1);
            acc1 = MFMA(ah, b1l, acc1);
            acc1 = MFMA(al, b1h, acc1);
        }
    };

    int nk = K >> 5;
    stage(0, 0);
    stage(1, 32);
    int t = 0;
    for (; t < nk - 1; ++t) {
        SYNC_CNT_LIT(6);
        if (t + 2 < nk) stage((t + 2) % 3, (t + 2) << 5);
        compute(t % 3);
    }
    SYNC_STEP();
    compute(t % 3);

    auto epi = [&](const f32x16& a, int ncol) {
        int col = n0 + ncol + lq;
        int rb2 = m0 + (wid >> 1) * 32 + (hi << 2);
#pragma unroll
        for (int r = 0; r < 16; ++r) {
            int row = rb2 + (r & 3) + ((r >> 2) << 3);
            float v = a[r];
            size_t o = (size_t)row * N + col;
            if (MODE == 1) C[o] = v + bias[col] + auxf[(size_t)(row & 1023) * N + col];
            else if (MODE == 2) C[o] = res[o] + (bf2f(auxh[o]) + bf2f(auxl[o])) + v + bias[col];
            else if (MODE == 4) C[o] = res[o] + v + bias[col];
            else if (MODE == 5) {
                v += bias[col];
                v = fmaxf(v, 0.0f);
                split2(v, Ch[o], Cl[o]);
            }
            else if (MODE == 6) C[o] = v + bias[col];
        }
    };
    epi(acc0, (wid & 1) * 64);
    epi(acc1, (wid & 1) * 64 + 32);
}

// ---------------- gemm_sq: 128x128 tile, 4 waves of 64x64, 2-buf drain ----------------
template <int MODE>
__global__ __launch_bounds__(256, 2) void gemm_sq(const u16* __restrict__ Ah, const u16* __restrict__ Al,
                                                  const u16* __restrict__ Bh, const u16* __restrict__ Bl,
                                                  const float* __restrict__ bias,
                                                  u16* __restrict__ Ch, u16* __restrict__ Cl,
                                                  u16* __restrict__ Cth, u16* __restrict__ Ctl,
                                                  int M, int N, int K, int nby) {
    __shared__ u16 SH[32768];
    int tid = threadIdx.x;
    int wid = tid >> 6, lane = tid & 63;
    int hi = lane >> 5;
    int lq = lane & 31;
    int wm = wid >> 1, wn = wid & 1;

    int nwg = gridDim.x;
    int q8 = nwg >> 3;
    int swz = (blockIdx.x & 7) * q8 + (blockIdx.x >> 3);
    int cb = swz / nby, rb = swz - cb * nby;
    int m0 = rb * 128, n0 = cb * 128;

    f32x16 acc00 = {}, acc01 = {}, acc10 = {}, acc11 = {};

    const u16* srcs[4] = {Ah, Al, Bh, Bl};
    auto stage = [&](int buf, int kt) {
        const u16* G = srcs[wid];
        int rbase = (wid < 2) ? m0 : n0;
#pragma unroll
        for (int i = 0; i < 8; ++i) {
            int row = i * 16 + (lane >> 2);
            int ch = (lane & 3) ^ mrow(row);
            const u16* g = G + (size_t)(rbase + row) * K + kt + ch * 8;
            __builtin_amdgcn_global_load_lds((const __attribute__((address_space(1))) u32*)g,
                                             (__attribute__((address_space(3))) u32*)&SH[buf * 16384 + wid * 4096 + i * 512],
                                             16, 0, 0);
        }
    };

    int ar0 = wm * 64 + lq, ar1 = ar0 + 32;
    int br0 = wn * 64 + lq, br1 = br0 + 32;

    auto compute = [&](int buf) {
        const u16* SAh = SH + buf * 16384;
        const u16* SAl = SAh + 4096;
        const u16* SBh = SAl + 4096;
        const u16* SBl = SBh + 4096;
#pragma unroll
        for (int kc = 0; kc < 2; ++kc) {
            int gc = (kc << 1) | hi;
            int oA0 = ar0 * 32 + ((gc ^ mrow(ar0)) << 3);
            int oA1 = ar1 * 32 + ((gc ^ mrow(ar1)) << 3);
            int oB0 = br0 * 32 + ((gc ^ mrow(br0)) << 3);
            int oB1 = br1 * 32 + ((gc ^ mrow(br1)) << 3);
            bf16x8 a0h = *(const bf16x8*)(SAh + oA0);
            bf16x8 a0l = *(const bf16x8*)(SAl + oA0);
            bf16x8 a1h = *(const bf16x8*)(SAh + oA1);
            bf16x8 a1l = *(const bf16x8*)(SAl + oA1);
            bf16x8 b0h = *(const bf16x8*)(SBh + oB0);
            bf16x8 b0l = *(const bf16x8*)(SBl + oB0);
            bf16x8 b1h = *(const bf16x8*)(SBh + oB1);
            bf16x8 b1l = *(const bf16x8*)(SBl + oB1);
            acc00 = MFMA(a0h, b0h, acc00);
            acc00 = MFMA(a0h, b0l, acc00);
            acc00 = MFMA(a0l, b0h, acc00);
            acc01 = MFMA(a0h, b1h, acc01);
            acc01 = MFMA(a0h, b1l, acc01);
            acc01 = MFMA(a0l, b1h, acc01);
            acc10 = MFMA(a1h, b0h, acc10);
            acc10 = MFMA(a1h, b0l, acc10);
            acc10 = MFMA(a1l, b0h, acc10);
            acc11 = MFMA(a1h, b1h, acc11);
            acc11 = MFMA(a1h, b1l, acc11);
            acc11 = MFMA(a1l, b1h, acc11);
        }
    };

    int nk = K >> 5;
    stage(0, 0);
    for (int t = 0; t < nk; ++t) {
        SYNC_STEP();
        if (t + 1 < nk) stage((t + 1) & 1, (t + 1) << 5);
        compute(t & 1);
    }

    if (MODE == 7 && n0 >= 1536) {
        int bb = m0 >> 10;
        int nbase = m0 & 1023;
#pragma unroll
        for (int P = 0; P < 2; ++P) {
            __syncthreads();
            if (wm == P) {
                auto scat = [&](const f32x16& a, int fm, int fn) {
                    int c = wn * 64 + fn * 32 + lq;
                    int rbl = fm * 32 + (hi << 2);
#pragma unroll
                    for (int r = 0; r < 16; ++r) {
                        int rr = rbl + (r & 3) + ((r >> 2) << 3);
                        u16 hv, lv;
                        split2(a[r], hv, lv);
                        SH[c * 68 + rr] = hv;
                        SH[8704 + c * 68 + rr] = lv;
                    }
                };
                scat(acc00, 0, 0); scat(acc01, 0, 1); scat(acc10, 1, 0); scat(acc11, 1, 1);
            }
            __syncthreads();
#pragma unroll
            for (int pass = 0; pass < 4; ++pass) {
                int c2 = pass * 32 + (tid >> 3);
                int ch8 = tid & 7;
                int hcol = (n0 - 1536) + c2;
                int h2 = hcol >> 6, hd = hcol & 63;
                size_t dst = ((size_t)(bb * 12 + h2) * 64 + hd) * 1024 + nbase + P * 64 + ch8 * 8;
                int so = c2 * 68 + ch8 * 8;
                u32x4 ph = {*(const u32*)&SH[so], *(const u32*)&SH[so + 2],
                            *(const u32*)&SH[so + 4], *(const u32*)&SH[so + 6]};
                u32x4 pl = {*(const u32*)&SH[8704 + so], *(const u32*)&SH[8704 + so + 2],
                            *(const u32*)&SH[8704 + so + 4], *(const u32*)&SH[8704 + so + 6]};
                *(u32x4*)(Cth + dst) = ph;
                *(u32x4*)(Ctl + dst) = pl;
            }
        }
        return;
    }

    auto epi = [&](const f32x16& a, int fm, int fn) {
        int col = n0 + wn * 64 + fn * 32 + lq;
        int rb2 = m0 + wm * 64 + fm * 32 + (hi << 2);
#pragma unroll
        for (int r = 0; r < 16; ++r) {
            int row = rb2 + (r & 3) + ((r >> 2) << 3);
            float v = a[r];
            if (MODE == 3) {
                size_t o = (size_t)row * N + col;
                v += bias[col];
                v = 0.5f * v * (1.0f + erff(v * 0.70710678118654752f));
                split2(v, Ch[o], Cl[o]);
            } else if (MODE == 7) {
                size_t o7 = (size_t)row * 1536 + col;
                split2(v, Ch[o7], Cl[o7]);
            }
        }
    };
    epi(acc00, 0, 0); epi(acc01, 0, 1); epi(acc10, 1, 0); epi(acc11, 1, 1);
}

// ---------------- MFMA flash attention: 64-row K-tiles, 8 steps, single-buffer 64KB ----------------
// grid 384 (8 xcd x 3 bh x 16 qt), 4 waves (s=q-half, p=K-parity over 64-row tiles)
__global__ __launch_bounds__(256, 2) void attn_mfma(const u16* __restrict__ qh, const u16* __restrict__ ql,
                                                    const u16* __restrict__ vth, const u16* __restrict__ vtl,
                                                    const float* __restrict__ biasT,
                                                    u16* __restrict__ oh, u16* __restrict__ ol) {
    __shared__ u16 smem[2][4][4096];     // [p][Kh,Kl,Vh,Vl][64x64] = 64 KB
    int tid = threadIdx.x;
    int wid = tid >> 6, lane = tid & 63;
    int s = wid & 1, p = wid >> 1;
    int lq = lane & 31;
    int hi = lane >> 5;
    int id = blockIdx.x;
    int xcd = id & 7;
    int j = id >> 3;
    int bh = xcd * 3 + (j >> 4);
    int qt = j & 15;
    int b = bh / 12, h = bh % 12;
    int bq0 = qt * 64;
    int gq = bq0 + s * 32 + lq;
    size_t vbase = (size_t)bh * 65536;   // Vt [64 hd][1024 k]

    bf16x8 qfh[4], qfl[4];
    {
        size_t qo = (size_t)(b * 1024 + gq) * 1536 + h * 64 + hi * 8;
#pragma unroll
        for (int ks = 0; ks < 4; ++ks) {
            qfh[ks] = *(const bf16x8*)(qh + qo + ks * 16);
            qfl[ks] = *(const bf16x8*)(ql + qo + ks * 16);
        }
    }

    f32x16 oa = {}, ob = {};
    float m_i = -1e30f, l_i = 0.0f;

    // stage one 64-row tile at kb into smem[p]: s=0 K (64 k-rows x 64 hd),
    // s=1 V^T (64 hd-rows x 64 k). Both 128B rows, 8-chunk XOR swizzle.
    auto stage = [&](int kb) {
        if (s == 0) {
#pragma unroll
            for (int c = 0; c < 2; ++c) {
                const u16* G = c ? ql : qh;
#pragma unroll
                for (int i = 0; i < 8; ++i) {
                    int r = 8 * i + (lane >> 3);
                    int cl = (lane & 7) ^ (r & 7);
                    const u16* g = G + (size_t)(b * 1024 + kb + r) * 1536 + 768 + h * 64 + cl * 8;
                    __builtin_amdgcn_global_load_lds((const __attribute__((address_space(1))) u32*)g,
                                                     (__attribute__((address_space(3))) u32*)&smem[p][c][i * 512],
                                                     16, 0, 0);
                }
            }
        } else {
#pragma unroll
            for (int c = 0; c < 2; ++c) {
                const u16* G = c ? vtl : vth;
#pragma unroll
                for (int i = 0; i < 8; ++i) {
                    int r = 8 * i + (lane >> 3);
                    int cl = (lane & 7) ^ (r & 7);
                    const u16* g = G + vbase + (size_t)r * 1024 + kb + cl * 8;
                    __builtin_amdgcn_global_load_lds((const __attribute__((address_space(1))) u32*)g,
                                                     (__attribute__((address_space(3))) u32*)&smem[p][2 + c][i * 512],
                                                     16, 0, 0);
                }
            }
        }
    };

    auto compute = [&](int kb) {
        const u16* Kh = &smem[p][0][0];
        const u16* Kl = &smem[p][1][0];
        const u16* Vh = &smem[p][2][0];
        const u16* Vl = &smem[p][3][0];
        // bias loads (32, coalesced in q) — issued first, consumed after QK block
        const float* bbase = biasT + (size_t)(kb + 4 * hi) * 1024 + gq;
        float bb[32];
#pragma unroll
        for (int g2 = 0; g2 < 4; ++g2)
#pragma unroll
            for (int q = 0; q < 4; ++q) {
                bb[g2 * 4 + q]      = bbase[(size_t)(g2 * 8 + q) * 1024];
                bb[16 + g2 * 4 + q] = bbase[(size_t)(32 + g2 * 8 + q) * 1024];
            }
        // QK^T: sa = k-rows 0..31, sb = k-rows 32..63 (independent chains)
        f32x16 sa = {}, sb = {};
#pragma unroll
        for (int ks = 0; ks < 4; ++ks) {
            int offA = lq * 64 + (((2 * ks + hi) ^ (lq & 7)) << 3);
            int offB = offA + 2048;                 // row lq+32, same swizzle ((lq+32)&7==lq&7)
            bf16x8 khA = *(const bf16x8*)(Kh + offA);
            bf16x8 klA = *(const bf16x8*)(Kl + offA);
            bf16x8 khB = *(const bf16x8*)(Kh + offB);
            bf16x8 klB = *(const bf16x8*)(Kl + offB);
            sa = MFMA(khA, qfh[ks], sa);
            sb = MFMA(khB, qfh[ks], sb);
            sa = MFMA(khA, qfl[ks], sa);
            sb = MFMA(khB, qfl[ks], sb);
            sa = MFMA(klA, qfh[ks], sa);
            sb = MFMA(klB, qfh[ks], sb);
        }
        // V fragments (ds_read latency hides under softmax)
        bf16x8 vf[4][4];
#pragma unroll
        for (int kslot = 0; kslot < 4; ++kslot) {
            int off0 = lq * 64 + (((2 * kslot + hi) ^ (lq & 7)) << 3);
            int off1 = off0 + 2048;
            vf[kslot][0] = *(const bf16x8*)(Vh + off0);
            vf[kslot][1] = *(const bf16x8*)(Vh + off1);
            vf[kslot][2] = *(const bf16x8*)(Vl + off0);
            vf[kslot][3] = *(const bf16x8*)(Vl + off1);
        }
        // scale + bias
#pragma unroll
        for (int r = 0; r < 16; ++r) {
            sa[r] = sa[r] * 0.125f + bb[r];
            sb[r] = sb[r] * 0.125f + bb[16 + r];
        }
        // softmax over 64 keys (lane <-> q)
        float pm = fmaxf(sa[0], sb[0]);
#pragma unroll
        for (int r = 1; r < 16; ++r) pm = fmaxf(pm, fmaxf(sa[r], sb[r]));
        pm = fmaxf(pm, __shfl_xor(pm, 32));
        if (__any(pm > m_i + 8.0f)) {
            float mnew = fmaxf(m_i, pm);
            float scl = __expf(m_i - mnew);
            m_i = mnew;
            l_i *= scl;
#pragma unroll
            for (int r = 0; r < 16; ++r) {
                int qr = (r & 3) + 8 * (r >> 2) + 4 * hi;
                float fr = __shfl(scl, qr);
                oa[r] *= fr; ob[r] *= fr;
            }
        }
        float ls = 0.0f;
#pragma unroll
        for (int r = 0; r < 16; ++r) {
            sa[r] = __expf(sa[r] - m_i); ls += sa[r];
            sb[r] = __expf(sb[r] - m_i); ls += sb[r];
        }
        ls += __shfl_xor(ls, 32);
        l_i += ls;
        // P repack + PV, 4 k-slots
#pragma unroll
        for (int kslot = 0; kslot < 4; ++kslot) {
            bf16x8 ph, pl;
            if (kslot < 2) repack(sa, (kslot & 1) * 8, hi, ph, pl);
            else           repack(sb, (kslot & 1) * 8, hi, ph, pl);
            oa = MFMA(ph, vf[kslot][0], oa);
            oa = MFMA(ph, vf[kslot][2], oa);
            oa = MFMA(pl, vf[kslot][0], oa);
            ob = MFMA(ph, vf[kslot][1], ob);
            ob = MFMA(ph, vf[kslot][3], ob);
            ob = MFMA(pl, vf[kslot][1], ob);
        }
    };

    // parity p handles 64-row tiles kt = 2*ss+p, ss = 0..7
    stage(p * 64);
    for (int ss = 0; ss < 8; ++ss) {
        SYNC_STEP();                         // stage(ss) landed
        compute((2 * ss + p) * 64);
        __syncthreads();                     // all readers done -> safe to overwrite
        if (ss + 1 < 8) stage((2 * (ss + 1) + p) * 64);
    }

    // ---- merge K-parity halves (smem reused as scratch; compute all done) ----
    float* mlb = (float*)((char*)smem + 32768);   // [s][p][2][32] floats
    mlb[((s * 2 + p) * 2 + 0) * 32 + lq] = m_i;
    mlb[((s * 2 + p) * 2 + 1) * 32 + lq] = l_i;
    __syncthreads();
    float mo  = mlb[((s * 2 + (p ^ 1)) * 2 + 0) * 32 + lq];
    float lo_ = mlb[((s * 2 + (p ^ 1)) * 2 + 1) * 32 + lq];
    float M = fmaxf(m_i, mo);
    float ea = __expf(m_i - M), eb = __expf(mo - M);
    float L = ea * l_i + eb * lo_;
    float f = ea / L;
    float frv[16];
#pragma unroll
    for (int r = 0; r < 16; ++r) frv[r] = __shfl(f, (r & 3) + 8 * (r >> 2) + 4 * hi);
    float* ox = (float*)((char*)smem + s * 8192);  // 32q x 64hd f32 per s
    if (p == 1) {
#pragma unroll
        for (int r = 0; r < 16; ++r) {
            int qr = (r & 3) + 8 * (r >> 2) + 4 * hi;
            ox[qr * 64 + lq] = oa[r] * frv[r];
            ox[qr * 64 + 32 + lq] = ob[r] * frv[r];
        }
    }
    __syncthreads();
    if (p == 0) {
#pragma unroll
        for (int r = 0; r < 16; ++r) {
            int qr = (r & 3) + 8 * (r >> 2) + 4 * hi;
            float va = oa[r] * frv[r] + ox[qr * 64 + lq];
            float vb = ob[r] * frv[r] + ox[qr * 64 + 32 + lq];
            size_t d = (size_t)(b * 1024 + bq0 + s * 32 + qr) * 768 + h * 64;
            split2(va, oh[d + lq], ol[d + lq]);
            split2(vb, oh[d + 32 + lq], ol[d + 32 + lq]);
        }
    }
}

// ---------------- fold + attention gate ----------------
__global__ __launch_bounds__(256) void fold_gate(const float* __restrict__ hbuf,
                                                 const float* __restrict__ xin,
                                                 const float* __restrict__ wg,
                                                 const float* __restrict__ bngw,
                                                 const float* __restrict__ bngb,
                                                 const float* __restrict__ wx,
                                                 const float* __restrict__ bnxw,
                                                 const float* __restrict__ bnxb,
                                                 const float* __restrict__ psiw,
                                                 const float* __restrict__ psib,
                                                 float* __restrict__ out) {
    int idx = blockIdx.x * 256 + threadIdx.x;      // < 2*512*512
    int b = idx >> 18;
    int rem = idx & 262143;
    int hh = rem >> 9, ww = rem & 511;
    int n = ((hh >> 4) << 5) + (ww >> 4);
    int pr = hh & 15, pc = ww & 15;
    const float* hrow = hbuf + (size_t)(b * 1024 + n) * 768 + pr * 16 + pc;
    float g0 = hrow[0], g1 = hrow[256], g2 = hrow[512];
    size_t xoff = ((size_t)(b * 3) * 512 + hh) * 512 + ww;
    float x0 = xin[xoff], x1 = xin[xoff + 262144], x2 = xin[xoff + 524288];
    float inv = rsqrtf(1.0f + 1e-5f);
    float gg = (g0 * wg[0] + g1 * wg[1] + g2 * wg[2]) * inv * bngw[0] + bngb[0];
    float xx = (x0 * wx[0] + x1 * wx[1] + x2 * wx[2]) * inv * bnxw[0] + bnxb[0];
    float z = gg + xx;
    z = z > 0.0f ? z : 0.0f;
    float psi = 1.0f / (1.0f + expf(-(z * psiw[0] + psib[0])));
    out[xoff]          = g0 * x0 * psi;
    out[xoff + 262144] = g1 * x1 * psi;
    out[xoff + 524288] = g2 * x2 * psi;
}

// ---------------- launch ----------------
extern "C" void kernel_launch(void* const* d_in, const int* in_sizes, int n_in,
                              void* d_out, int out_size, void* d_ws, size_t ws_size,
                              hipStream_t stream) {
    (void)in_sizes; (void)n_in; (void)out_size; (void)ws_size;
    const float* x       = (const float*)d_in[0];
    const float* conv_w  = (const float*)d_in[1];
    const float* conv_b  = (const float*)d_in[2];
    const float* ln1_g   = (const float*)d_in[3];
    const float* ln1_b   = (const float*)d_in[4];
    const float* qkv_w   = (const float*)d_in[5];
    const float* proj_w  = (const float*)d_in[6];
    const float* proj_b  = (const float*)d_in[7];
    const float* attn_bs = (const float*)d_in[8];
    const float* ln2_g   = (const float*)d_in[9];
    const float* ln2_b   = (const float*)d_in[10];
    const float* mlp_w1  = (const float*)d_in[11];
    const float* mlp_b1  = (const float*)d_in[12];
    const float* mlp_w2  = (const float*)d_in[13];
    const float* mlp_b2  = (const float*)d_in[14];
    const float* op_w1   = (const float*)d_in[15];
    const float* op_b1   = (const float*)d_in[16];
    const float* op_w2   = (const float*)d_in[17];
    const float* op_b2   = (const float*)d_in[18];
    const float* ag_wg   = (const float*)d_in[19];
    const float* ag_bngw = (const float*)d_in[20];
    const float* ag_bngb = (const float*)d_in[21];
    const float* ag_wx   = (const float*)d_in[22];
    const float* ag_bnxw = (const float*)d_in[23];
    const float* ag_bnxb = (const float*)d_in[24];
    const float* ag_psiw = (const float*)d_in[25];
    const float* ag_psib = (const float*)d_in[26];
    float* out = (float*)d_out;

    // workspace layout (bytes), total 67,108,864
    char* w8 = (char*)d_ws;
    float* t     = (float*)(w8);                      // 6,291,456
    u16* yh      = (u16*)(w8 + 6291456);
    u16* yl      = (u16*)(w8 + 9437184);
    u16* ath     = (u16*)(w8 + 12582912);
    u16* atl     = (u16*)(w8 + 15728640);
    u16* mh      = (u16*)(w8 + 18874368);             // 6,291,456
    u16* ml      = (u16*)(w8 + 25165824);             // 6,291,456
    u16* qh      = (u16*)(w8 + 31457280);             // 6,291,456 (2048x1536 u16)
    u16* ql      = (u16*)(w8 + 37748736);             // 6,291,456
    u16* wh      = (u16*)(w8 + 44040192);             // 9,437,184
    u16* wl      = (u16*)(w8 + 53477376);             // 9,437,184
    float* biasT = (float*)(w8 + 62914560);           // 4,194,304
    float* pe  = (float*)qh;
    u16* xph = mh; u16* xpl = ml;
    u16* vth = mh; u16* vtl = ml;
    float* oph2 = (float*)qh;
    u16* o1h = ath; u16* o1l = atl;

    const size_t W_QKV = 0, W_PROJ = 1769472, W_MLP1 = 2359296, W_MLP2 = 3538944;

    pe_kernel<<<3072, 256, 0, stream>>>(pe);
    gather_kernel<<<6144, 256, 0, stream>>>(x, xph, xpl);
    fsplit<<<576, 256, 0, stream>>>(conv_w, wh, wl, 147456);
    gemm_sp<1><<<192, 256, 0, stream>>>(xph, xpl, wh, wl, conv_b, nullptr, pe,
                                        nullptr, nullptr, t, nullptr, nullptr, 2048, 768, 768, 32);

    for (int l = 0; l < 8; ++l) {
        wsplit_layer<<<4608, 256, 0, stream>>>(qkv_w + (size_t)l * 1769472, proj_w + (size_t)l * 589824,
                                               mlp_w1 + (size_t)l * 1179648, mlp_w2 + (size_t)l * 1179648,
                                               wh, wl);
        btrans<<<1024, 256, 0, stream>>>(attn_bs + (size_t)l * 1048576, biasT);
        ln_kernel<<<2048, 256, 0, stream>>>(t, ln1_g + l * 768, ln1_b + l * 768, yh, yl);
        gemm_sq<7><<<288, 256, 0, stream>>>(yh, yl, wh + W_QKV, wl + W_QKV, nullptr,
                                            qh, ql, vth, vtl, 2048, 2304, 768, 16);
        attn_mfma<<<384, 256, 0, stream>>>(qh, ql, vth, vtl, biasT, ath, atl);
        gemm_sp<2><<<192, 256, 0, stream>>>(ath, atl, wh + W_PROJ, wl + W_PROJ, proj_b + l * 768,
                                            t, nullptr, yh, yl, t, nullptr, nullptr, 2048, 768, 768, 32);
        ln_kernel<<<2048, 256, 0, stream>>>(t, ln2_g + l * 768, ln2_b + l * 768, yh, yl);
        gemm_sq<3><<<192, 256, 0, stream>>>(yh, yl, wh + W_MLP1, wl + W_MLP1, mlp_b1 + l * 1536,
                                            mh, ml, nullptr, nullptr, 2048, 1536, 768, 16);
        gemm_sp<4><<<192, 256, 0, stream>>>(mh, ml, wh + W_MLP2, wl + W_MLP2, mlp_b2 + l * 768,
                                            t, nullptr, nullptr, nullptr, t, nullptr, nullptr,
                                            2048, 768, 1536, 32);
    }

    // output head
    fsplit<<<1536, 256, 0, stream>>>(t, yh, yl, 393216);
    fsplit<<<96, 256, 0, stream>>>(op_w1, wh, wl, 24576);
    fsplit<<<96, 256, 0, stream>>>(op_w2, wh + 131072, wl + 131072, 24576);
    gemm_sp<5><<<32, 256, 0, stream>>>(yh, yl, wh, wl, op_b1, nullptr, nullptr,
                                       nullptr, nullptr, nullptr, o1h, o1l, 2048, 128, 768, 32);
    gemm_sp<6><<<192, 256, 0, stream>>>(o1h, o1l, wh + 131072, wl + 131072, op_b2, nullptr,
                                        nullptr, nullptr, nullptr, oph2, nullptr, nullptr,
                                        2048, 768, 128, 32);
    fold_gate<<<2048, 256, 0, stream>>>(oph2, x, ag_wg, ag_bngw, ag_bngb,
                                        ag_wx, ag_bnxw, ag_bnxb, ag_psiw, ag_psib, out);
}